// Round 4
// baseline (3320.285 us; speedup 1.0000x reference)
//
#include <hip/hip_runtime.h>
#include <stdint.h>

#define B_ 4096
#define T_ 80
#define E_ 100
#define V_ 10000
#define U_ 1024

typedef unsigned short u16;
typedef __attribute__((ext_vector_type(8))) __bf16 bf16x8;
typedef __attribute__((ext_vector_type(4))) float f32x4;

__device__ __forceinline__ float bf2f(u16 u) {
    union { unsigned int i; float f; } v; v.i = ((unsigned int)u) << 16; return v.f;
}
__device__ __forceinline__ u16 f2bf(float f) {
    union { float f; unsigned int i; } v; v.f = f;
    unsigned int x = v.i;
    return (u16)((x + 0x7fffu + ((x >> 16) & 1u)) >> 16);
}

// async global->LDS, 16 B per lane; LDS dest = wave-uniform base + lane*16 (m104 semantics).
__device__ __forceinline__ void load16(const void* g, void* l) {
    __builtin_amdgcn_global_load_lds(
        (__attribute__((address_space(1))) void*)(uintptr_t)g,
        (__attribute__((address_space(3))) void*)(uint32_t)(uintptr_t)l,
        16, 0, 0);
}

// dst[n*Kp + k] = bf16( (k < K) ? src[k*N + n] : 0 )
__global__ void transpose_pad(const float* __restrict__ src, u16* __restrict__ dst,
                              int K, int N, int Kp)
{
    __shared__ u16 tile[32][33];
    const int k0 = blockIdx.x * 32;
    const int n0 = blockIdx.y * 32;
    const int tx = threadIdx.x & 31;
    const int ty = threadIdx.x >> 5;
#pragma unroll
    for (int i = 0; i < 4; i++) {
        int k = k0 + ty + i * 8;
        tile[ty + i * 8][tx] = (k < K) ? f2bf(src[(size_t)k * N + (n0 + tx)]) : (u16)0;
    }
    __syncthreads();
#pragma unroll
    for (int i = 0; i < 4; i++) {
        int n = n0 + ty + i * 8;
        dst[(size_t)n * Kp + (k0 + tx)] = tile[tx][ty + i * 8];
    }
}

__global__ void embed_pad(const float* __restrict__ emb, u16* __restrict__ dst)
{
    int id = blockIdx.x * 256 + threadIdx.x;
    int v = id >> 7, k = id & 127;
    dst[id] = (k < E_) ? f2bf(emb[v * E_ + k]) : (u16)0;
}

// Fused phase p (independent sub-steps):
//   layer0: h0[p]   = tanh(embP[idx_p] @ Wx0 + h0[p-1] @ Wh0 + b0)   (if do0)
//   layer1: h1[p-1] = tanh(h0[p-1] @ Wx1 + h1[p-2] @ Wh1 + b1)       (if do1)
// r14: counted-vmcnt deep prefetch (T4 mechanism) with minimal delta from the 2818-us
// baseline. Evidence trail: r12 (layer balance) neutral -> not imbalance-bound;
// r13 (XCD n0) -9% -> not L2-B-thrash-bound (reverted); HBM ~0, conflicts 0.
// Diagnosis: iteration-top __syncthreads() drains vmcnt(0); stage(u+1) has only ~1 loop
// body (~400 cyc) to cover its L2/L3 round-trip (~200-900 cyc under ~11 TB/s load) ->
// every K-tile eats exposed latency; MFMA pipe ~12% on busiest CUs.
// Fix: BK 64->32, FOUR LDS slots (4 x 16 KB = 64 KB, 2 blocks/CU UNCHANGED), 3-tile
// lookahead. Iter u: s_waitcnt vmcnt(8) lgkmcnt(0) (tile u complete; u+1,u+2 in flight,
// never drains), raw s_barrier, then issue stage(u+3). lgkmcnt(0) before the barrier
// guarantees all reads of the recycled slot completed before any wave's DMA overwrites it.
// Swizzle: 4-chunk domain, s(row) = (row + (row>>2)) & 3; stored chunk c holds source
// chunk c^s(row); verified 2-way bank aliasing (free, m136). Unlike r11: 2 blocks/CU,
// 1 barrier/tile, no setprio, no phase split.
__global__ void __launch_bounds__(256, 2)
rnn_phase(const u16* __restrict__ embP, const int* __restrict__ idx,
          const u16* __restrict__ Wx0T, const u16* __restrict__ Wh0T, const float* __restrict__ b0,
          const u16* __restrict__ Wx1T, const u16* __restrict__ Wh1T, const float* __restrict__ b1,
          const u16* __restrict__ h0r, u16* __restrict__ h0w,
          const u16* __restrict__ h1r, u16* __restrict__ h1w,
          int do0, int do1)
{
    const int linear = blockIdx.x;        // 0..511
    const int layer  = linear >> 8;       // 0..255 -> layer0, 256..511 -> layer1
    if (layer ? !do1 : !do0) return;

    __shared__ u16 As[4][128 * 32];   // 4 x 8 KB
    __shared__ u16 Bs[4][128 * 32];   // 4 x 8 KB
    const int tid  = threadIdx.x;
    const int lane = tid & 63;
    const int wave = tid >> 6;
    const int wm = wave >> 1, wn = wave & 1;
    const int sub = linear & 255;
    const int m0 = (sub & 31) * 128;
    const int n0 = (sub >> 5) * 128;

    const u16 *A1, *W1, *A2, *W2; const float* bias; u16* C; int K1; bool gather;
    if (layer == 0) { A1 = embP; W1 = Wx0T; K1 = 128;  gather = true;  A2 = h0r; W2 = Wh0T; bias = b0; C = h0w; }
    else            { A1 = h0r;  W1 = Wx1T; K1 = 1024; gather = false; A2 = h1r; W2 = Wh1T; bias = b1; C = h1w; }
    const int KB1 = K1 >> 5;            // 32-wide K blocks in the first segment
    const int TOT = KB1 + (U_ >> 5);    // + 32 for the hidden segment

    // staging lane map: call covers 16 rows x 32 elems (1 KB); row += lane>>2, chunk lane&3.
    const int r4 = lane >> 2;           // 0..15
    const int c4 = lane & 3;            // 16B chunk 0..3

    int gv[2];
    if (gather) {
#pragma unroll
        for (int cc = 0; cc < 2; cc++)
            gv[cc] = idx[(size_t)(m0 + wave * 32 + cc * 16 + r4) * T_];
    }

    const f32x4 z = {0.f, 0.f, 0.f, 0.f};
    f32x4 acc[4][4];
#pragma unroll
    for (int i = 0; i < 4; i++)
#pragma unroll
        for (int j = 0; j < 4; j++) acc[i][j] = z;

    // loop-invariant fragment read offsets (u16 elems), inverse-swizzled.
    // position p = q ^ s(row) holds source chunk q, s(row) = (row + (row>>2)) & 3.
    const int l15 = lane & 15, q = lane >> 4;   // q in 0..3 -> K offset q*8
    int offA[4], offB[4];
#pragma unroll
    for (int f = 0; f < 4; f++) {
        const int rA = wm * 64 + f * 16 + l15;
        const int rB = wn * 64 + f * 16 + l15;
        offA[f] = rA * 32 + ((q ^ ((rA + (rA >> 2)) & 3)) * 8);
        offB[f] = rB * 32 + ((q ^ ((rB + (rB >> 2)) & 3)) * 8);
    }

    auto stage = [&](int u) {
        const int slot = u & 3;
        u16* Ad = As[slot] + wave * 1024;   // 32 rows x 32 elems per wave
        u16* Bd = Bs[slot] + wave * 1024;
        if (u < KB1) {
            const int k0 = u * 32;
#pragma unroll
            for (int cc = 0; cc < 2; cc++) {
                const int row = wave * 32 + cc * 16 + r4;
                const int sw  = ((c4 ^ ((row + (row >> 2)) & 3)) * 8);
                const u16* ap = gather ? A1 + (size_t)gv[cc] * 128 + k0 + sw
                                       : A1 + (size_t)(m0 + row) * K1 + k0 + sw;
                load16(ap, Ad + cc * 512);
                load16(W1 + (size_t)(n0 + row) * K1 + k0 + sw, Bd + cc * 512);
            }
        } else {
            const int k0 = (u - KB1) * 32;
#pragma unroll
            for (int cc = 0; cc < 2; cc++) {
                const int row = wave * 32 + cc * 16 + r4;
                const int sw  = ((c4 ^ ((row + (row >> 2)) & 3)) * 8);
                load16(A2 + (size_t)(m0 + row) * U_ + k0 + sw, Ad + cc * 512);
                load16(W2 + (size_t)(n0 + row) * U_ + k0 + sw, Bd + cc * 512);
            }
        }
    };

    // prologue: 3 tiles in flight (4 load16 per tile per wave)
    stage(0); stage(1); stage(2);

#pragma unroll 1
    for (int u = 0; u < TOT; ++u) {
        const int slot = u & 3;
        // tile u complete (own wave's 4 newest-minus-8 loads done); u+1,u+2 stay in flight.
        // lgkmcnt(0): this wave's previous ds_reads landed -> recycled slot safe to overwrite
        // after the barrier.
        if (u + 2 < TOT)      asm volatile("s_waitcnt vmcnt(8) lgkmcnt(0)" ::: "memory");
        else if (u + 1 < TOT) asm volatile("s_waitcnt vmcnt(4) lgkmcnt(0)" ::: "memory");
        else                  asm volatile("s_waitcnt vmcnt(0) lgkmcnt(0)" ::: "memory");
        __builtin_amdgcn_s_barrier();
        __builtin_amdgcn_sched_barrier(0);
        if (u + 3 < TOT) stage(u + 3);

        bf16x8 a[4], b[4];
#pragma unroll
        for (int f = 0; f < 4; f++) {
            a[f] = *reinterpret_cast<const bf16x8*>(As[slot] + offA[f]);
            b[f] = *reinterpret_cast<const bf16x8*>(Bs[slot] + offB[f]);
        }
#pragma unroll
        for (int i = 0; i < 4; i++)
#pragma unroll
            for (int j = 0; j < 4; j++)
                acc[i][j] = __builtin_amdgcn_mfma_f32_16x16x32_bf16(a[i], b[j], acc[i][j], 0, 0, 0);
    }

    // epilogue: bias + tanh, bf16 store (C/D map: col = lane&15, row = (lane>>4)*4 + reg)
#pragma unroll
    for (int j = 0; j < 4; j++) {
        const int col = n0 + wn * 64 + j * 16 + l15;
        const float bv = bias[col];
#pragma unroll
        for (int i = 0; i < 4; i++) {
#pragma unroll
            for (int r = 0; r < 4; r++) {
                const int row = m0 + wm * 64 + i * 16 + (q << 2) + r;
                float x = acc[i][j][r] + bv;
                x = fminf(15.f, fmaxf(-15.f, x));
                float e = __expf(2.f * x);
                C[(size_t)row * U_ + col] = f2bf((e - 1.f) / (e + 1.f));
            }
        }
    }
}

// out[b] = sigmoid( dot(h1[b,:], Wfc) + bfc ), one wave per row; f32 out
__global__ void final_dense(const u16* __restrict__ h1, const float* __restrict__ Wfc,
                            const float* __restrict__ bfc, float* __restrict__ out)
{
    const int lane = threadIdx.x & 63;
    const int wave = threadIdx.x >> 6;
    const int row = blockIdx.x * 4 + wave;
    const u16* hp = h1 + (size_t)row * U_ + lane * 16;
    const float* wp = Wfc + lane * 16;
    float s = 0.f;
#pragma unroll
    for (int i = 0; i < 16; i++) s += bf2f(hp[i]) * wp[i];
#pragma unroll
    for (int off = 32; off; off >>= 1) s += __shfl_down(s, off);
    if (lane == 0) {
        float x = s + bfc[0];
        out[row] = 1.f / (1.f + __expf(-x));
    }
}

extern "C" void kernel_launch(void* const* d_in, const int* in_sizes, int n_in,
                              void* d_out, int out_size, void* d_ws, size_t ws_size,
                              hipStream_t stream)
{
    const int*   inputs = (const int*)d_in[0];
    const float* emb    = (const float*)d_in[1];
    const float* Wx0    = (const float*)d_in[2];
    const float* Wh0    = (const float*)d_in[3];
    const float* b0     = (const float*)d_in[4];
    const float* Wx1    = (const float*)d_in[5];
    const float* Wh1    = (const float*)d_in[6];
    const float* b1     = (const float*)d_in[7];
    const float* Wfc    = (const float*)d_in[8];
    const float* bfc    = (const float*)d_in[9];

    char* ws = (char*)d_ws;
    const size_t MB = 1 << 20;
    u16* h0b[2] = { (u16*)(ws + 0 * MB), (u16*)(ws + 8 * MB) };   // 8 MB each
    u16* h1b[2] = { (u16*)(ws + 16 * MB), (u16*)(ws + 24 * MB) };
    u16* embP = (u16*)(ws + 32 * MB);  // 2.56 MB
    u16* Wx0T = (u16*)(ws + 35 * MB);  // [1024][128]
    u16* Wh0T = (u16*)(ws + 36 * MB);  // [1024][1024]
    u16* Wx1T = (u16*)(ws + 38 * MB);
    u16* Wh1T = (u16*)(ws + 40 * MB);  // ..42 MB

    // phase 0 reads h0[-1] from h0b[1]; phase 1 reads h1[-1] from h1b[1]
    hipMemsetAsync(h0b[1], 0, 8 * MB, stream);
    hipMemsetAsync(h1b[1], 0, 8 * MB, stream);

    embed_pad<<<V_ * 128 / 256, 256, 0, stream>>>(emb, embP);
    transpose_pad<<<dim3(128 / 32, U_ / 32), 256, 0, stream>>>(Wx0, Wx0T, E_, U_, 128);
    transpose_pad<<<dim3(U_ / 32, U_ / 32), 256, 0, stream>>>(Wh0, Wh0T, U_, U_, U_);
    transpose_pad<<<dim3(U_ / 32, U_ / 32), 256, 0, stream>>>(Wx1, Wx1T, U_, U_, U_);
    transpose_pad<<<dim3(U_ / 32, U_ / 32), 256, 0, stream>>>(Wh1, Wh1T, U_, U_, U_);

    // phase p: layer0 writes h0[p] -> h0b[p&1], reads h0[p-1] -> h0b[(p&1)^1];
    //          layer1 writes h1[p-1] -> h1b[(p&1)^1], reads h1[p-2] -> h1b[p&1]
    // 512 linear blocks: 0..255 layer0, 256..511 layer1.
    for (int p = 0; p <= T_; ++p) {
        const int e = p & 1;
        rnn_phase<<<512, 256, 0, stream>>>(embP, inputs + p,
                                           Wx0T, Wh0T, b0, Wx1T, Wh1T, b1,
                                           h0b[e ^ 1], h0b[e], h1b[e], h1b[e ^ 1],
                                           (int)(p < T_), (int)(p >= 1));
    }
    // h1[79] written at phase 80 into h1b[(80&1)^1] = h1b[1]
    final_dense<<<B_ / 4, 256, 0, stream>>>(h1b[1], Wfc, bfc, (float*)d_out);
}

// Round 6
// 3207.589 us; speedup vs baseline: 1.0351x; 1.0351x over previous
//
#include <hip/hip_runtime.h>
#include <stdint.h>

#define B_ 4096
#define T_ 80
#define E_ 100
#define V_ 10000
#define U_ 1024

typedef unsigned short u16;
typedef __attribute__((ext_vector_type(8))) __bf16 bf16x8;
typedef __attribute__((ext_vector_type(4))) float f32x4;

__device__ __forceinline__ float bf2f(u16 u) {
    union { unsigned int i; float f; } v; v.i = ((unsigned int)u) << 16; return v.f;
}
__device__ __forceinline__ u16 f2bf(float f) {
    union { float f; unsigned int i; } v; v.f = f;
    unsigned int x = v.i;
    return (u16)((x + 0x7fffu + ((x >> 16) & 1u)) >> 16);
}

// async global->LDS, 16 B per lane; LDS dest = wave-uniform base + lane*16 (m104 semantics).
__device__ __forceinline__ void load16(const void* g, void* l) {
    __builtin_amdgcn_global_load_lds(
        (__attribute__((address_space(1))) void*)(uintptr_t)g,
        (__attribute__((address_space(3))) void*)(uint32_t)(uintptr_t)l,
        16, 0, 0);
}

// dst[n*Kp + k] = bf16( (k < K) ? src[k*N + n] : 0 )
__global__ void transpose_pad(const float* __restrict__ src, u16* __restrict__ dst,
                              int K, int N, int Kp)
{
    __shared__ u16 tile[32][33];
    const int k0 = blockIdx.x * 32;
    const int n0 = blockIdx.y * 32;
    const int tx = threadIdx.x & 31;
    const int ty = threadIdx.x >> 5;
#pragma unroll
    for (int i = 0; i < 4; i++) {
        int k = k0 + ty + i * 8;
        tile[ty + i * 8][tx] = (k < K) ? f2bf(src[(size_t)k * N + (n0 + tx)]) : (u16)0;
    }
    __syncthreads();
#pragma unroll
    for (int i = 0; i < 4; i++) {
        int n = n0 + ty + i * 8;
        dst[(size_t)n * Kp + (k0 + tx)] = tile[tx][ty + i * 8];
    }
}

__global__ void embed_pad(const float* __restrict__ emb, u16* __restrict__ dst)
{
    int id = blockIdx.x * 256 + threadIdx.x;
    int v = id >> 7, k = id & 127;
    dst[id] = (k < E_) ? f2bf(emb[v * E_ + k]) : (u16)0;
}

// Fused phase p (independent sub-steps):
//   layer0: h0[p]   = tanh(embP[idx_p] @ Wx0 + h0[p-1] @ Wh0 + b0)   (if do0)
//   layer1: h1[p-1] = tanh(h0[p-1] @ Wx1 + h1[p-2] @ Wh1 + b1)       (if do1)
// r15b: resubmit of r15 (container infra failure, no counters; code re-audited: no
// barrier divergence, LDS 144 KB <= 160 KB, vmcnt ledger exact incl. tail iters).
// Theory: r10 loop is prefetch-depth-1 -> T_iter >= L3 latency (~650-900 cyc) >>
// compute (~350 cyc); measured ~900 cyc/tile with MFMA 9%, L2 ~32%, HBM ~1%
// (nothing saturated = latency wall). Fix: depth-2 counted-vmcnt prefetch on the
// r10-proven frame: BK=64, identical 8-chunk XOR swizzle + read pattern, ONE barrier
// per tile. New: BM=256 x BN=128 (staged traffic 419->314 MB/dispatch), 512 thr /
// 8 waves (4m x 2n, same 64x64 wave tile + epilogue), THREE LDS slots (144 KB,
// 1 block/CU, 2 waves/SIMD). Iter u: wait vmcnt(6) (= stage(u+1)'s 6 loads; never
// drains in steady state), s_barrier, issue stage(u+2) -> each stage has ~2 iters
// to cover latency. Slot recycle: (u+2)%3 last read in iter u-1, complete before
// barrier u. Layer = linear&1 keeps chunked-XCD n0 locality.
__global__ void __launch_bounds__(512, 1)
rnn_phase(const u16* __restrict__ embP, const int* __restrict__ idx,
          const u16* __restrict__ Wx0T, const u16* __restrict__ Wh0T, const float* __restrict__ b0,
          const u16* __restrict__ Wx1T, const u16* __restrict__ Wh1T, const float* __restrict__ b1,
          const u16* __restrict__ h0r, u16* __restrict__ h0w,
          const u16* __restrict__ h1r, u16* __restrict__ h1w,
          int do0, int do1)
{
    const int linear = blockIdx.x;        // 0..255
    const int layer  = linear & 1;
    if (layer ? !do1 : !do0) return;

    __shared__ u16 As[3][256 * 64];   // 3 x 32 KB
    __shared__ u16 Bs[3][128 * 64];   // 3 x 16 KB
    const int tid  = threadIdx.x;
    const int lane = tid & 63;
    const int wave = tid >> 6;            // 0..7
    const int wm = wave >> 1, wn = wave & 1;   // 4 x 2 wave grid, 64x64 each
    const int sub = linear >> 1;          // 0..127
    const int m0 = (sub & 15) * 256;
    const int n0 = (sub >> 4) * 128;

    const u16 *A1, *W1, *A2, *W2; const float* bias; u16* C; int K1; bool gather;
    if (layer == 0) { A1 = embP; W1 = Wx0T; K1 = 128;  gather = true;  A2 = h0r; W2 = Wh0T; bias = b0; C = h0w; }
    else            { A1 = h0r;  W1 = Wx1T; K1 = 1024; gather = false; A2 = h1r; W2 = Wh1T; bias = b1; C = h1w; }
    const int KB1 = K1 >> 6;            // 64-wide K blocks in the first segment
    const int TOT = KB1 + (U_ >> 6);    // + 16 for the hidden segment

    // staging lane map (r10-identical): row += lane>>3, chunk lane&7,
    // stored chunk c holds source chunk c ^ (row&7).
    const int r8 = lane >> 3;           // 0..7
    const int c8 = lane & 7;            // 16B chunk 0..7

    int gv[4];
    if (gather) {
#pragma unroll
        for (int cc = 0; cc < 4; cc++)
            gv[cc] = idx[(size_t)(m0 + wave * 32 + cc * 8 + r8) * T_];
    }

    const f32x4 z = {0.f, 0.f, 0.f, 0.f};
    f32x4 acc[4][4];
#pragma unroll
    for (int i = 0; i < 4; i++)
#pragma unroll
        for (int j = 0; j < 4; j++) acc[i][j] = z;

    // loop-invariant fragment read offsets (u16 elems), inverse-swizzled (r10-identical form)
    const int l15 = lane & 15, q = lane >> 4, l7 = lane & 7;
    int offA[2][4], offB[2][4];
#pragma unroll
    for (int kk = 0; kk < 2; kk++) {
#pragma unroll
        for (int f = 0; f < 4; f++) {
            const int rA = wm * 64 + f * 16 + l15;   // 0..255
            const int rB = wn * 64 + f * 16 + l15;   // 0..127
            offA[kk][f] = rA * 64 + (((kk * 4 + q) ^ l7) * 8);
            offB[kk][f] = rB * 64 + (((kk * 4 + q) ^ l7) * 8);
        }
    }

    // per stage: A rows [wave*32,+32) in 4 calls, B rows [wave*16,+16) in 2 calls -> 6 loads
    auto stage = [&](int u) {
        const int slot = u % 3;
        u16* Ad = As[slot] + wave * 2048;   // 32 rows x 64 elems
        u16* Bd = Bs[slot] + wave * 1024;   // 16 rows x 64 elems
        if (u < KB1) {
            const int k0 = u * 64;
#pragma unroll
            for (int cc = 0; cc < 4; cc++) {
                const int row = wave * 32 + cc * 8 + r8;
                const int scw = (c8 ^ (row & 7)) * 8;
                const u16* ap = gather ? A1 + (size_t)gv[cc] * 128 + k0 + scw
                                       : A1 + (size_t)(m0 + row) * K1 + k0 + scw;
                load16(ap, Ad + cc * 512);
            }
#pragma unroll
            for (int cc = 0; cc < 2; cc++) {
                const int row = wave * 16 + cc * 8 + r8;
                const int scw = (c8 ^ (row & 7)) * 8;
                load16(W1 + (size_t)(n0 + row) * K1 + k0 + scw, Bd + cc * 512);
            }
        } else {
            const int k0 = (u - KB1) * 64;
#pragma unroll
            for (int cc = 0; cc < 4; cc++) {
                const int row = wave * 32 + cc * 8 + r8;
                const int scw = (c8 ^ (row & 7)) * 8;
                load16(A2 + (size_t)(m0 + row) * U_ + k0 + scw, Ad + cc * 512);
            }
#pragma unroll
            for (int cc = 0; cc < 2; cc++) {
                const int row = wave * 16 + cc * 8 + r8;
                const int scw = (c8 ^ (row & 7)) * 8;
                load16(W2 + (size_t)(n0 + row) * U_ + k0 + scw, Bd + cc * 512);
            }
        }
    };

    // prologue: 2 tiles in flight (6 load16 per tile per wave)
    stage(0); stage(1);

#pragma unroll 1
    for (int u = 0; u < TOT; ++u) {
        const int slot = u % 3;
        // tile u ready when all but the newest 6 loads (= stage(u+1)) are done.
        if (u + 1 < TOT) asm volatile("s_waitcnt vmcnt(6)" ::: "memory");
        else             asm volatile("s_waitcnt vmcnt(0)" ::: "memory");
        __builtin_amdgcn_s_barrier();
        __builtin_amdgcn_sched_barrier(0);
        if (u + 2 < TOT) stage(u + 2);   // overwrites slot last read in iter u-1 (safe)

#pragma unroll
        for (int kk = 0; kk < 2; kk++) {
            bf16x8 a[4], b[4];
#pragma unroll
            for (int f = 0; f < 4; f++) {
                a[f] = *reinterpret_cast<const bf16x8*>(As[slot] + offA[kk][f]);
                b[f] = *reinterpret_cast<const bf16x8*>(Bs[slot] + offB[kk][f]);
            }
#pragma unroll
            for (int i = 0; i < 4; i++)
#pragma unroll
                for (int j = 0; j < 4; j++)
                    acc[i][j] = __builtin_amdgcn_mfma_f32_16x16x32_bf16(a[i], b[j], acc[i][j], 0, 0, 0);
        }
    }

    // epilogue: bias + tanh, bf16 store (C/D map: col = lane&15, row = (lane>>4)*4 + reg)
#pragma unroll
    for (int j = 0; j < 4; j++) {
        const int col = n0 + wn * 64 + j * 16 + l15;
        const float bv = bias[col];
#pragma unroll
        for (int i = 0; i < 4; i++) {
#pragma unroll
            for (int r = 0; r < 4; r++) {
                const int row = m0 + wm * 64 + i * 16 + (q << 2) + r;
                float x = acc[i][j][r] + bv;
                x = fminf(15.f, fmaxf(-15.f, x));
                float e = __expf(2.f * x);
                C[(size_t)row * U_ + col] = f2bf((e - 1.f) / (e + 1.f));
            }
        }
    }
}

// out[b] = sigmoid( dot(h1[b,:], Wfc) + bfc ), one wave per row; f32 out
__global__ void final_dense(const u16* __restrict__ h1, const float* __restrict__ Wfc,
                            const float* __restrict__ bfc, float* __restrict__ out)
{
    const int lane = threadIdx.x & 63;
    const int wave = threadIdx.x >> 6;
    const int row = blockIdx.x * 4 + wave;
    const u16* hp = h1 + (size_t)row * U_ + lane * 16;
    const float* wp = Wfc + lane * 16;
    float s = 0.f;
#pragma unroll
    for (int i = 0; i < 16; i++) s += bf2f(hp[i]) * wp[i];
#pragma unroll
    for (int off = 32; off; off >>= 1) s += __shfl_down(s, off);
    if (lane == 0) {
        float x = s + bfc[0];
        out[row] = 1.f / (1.f + __expf(-x));
    }
}

extern "C" void kernel_launch(void* const* d_in, const int* in_sizes, int n_in,
                              void* d_out, int out_size, void* d_ws, size_t ws_size,
                              hipStream_t stream)
{
    const int*   inputs = (const int*)d_in[0];
    const float* emb    = (const float*)d_in[1];
    const float* Wx0    = (const float*)d_in[2];
    const float* Wh0    = (const float*)d_in[3];
    const float* b0     = (const float*)d_in[4];
    const float* Wx1    = (const float*)d_in[5];
    const float* Wh1    = (const float*)d_in[6];
    const float* b1     = (const float*)d_in[7];
    const float* Wfc    = (const float*)d_in[8];
    const float* bfc    = (const float*)d_in[9];

    char* ws = (char*)d_ws;
    const size_t MB = 1 << 20;
    u16* h0b[2] = { (u16*)(ws + 0 * MB), (u16*)(ws + 8 * MB) };   // 8 MB each
    u16* h1b[2] = { (u16*)(ws + 16 * MB), (u16*)(ws + 24 * MB) };
    u16* embP = (u16*)(ws + 32 * MB);  // 2.56 MB
    u16* Wx0T = (u16*)(ws + 35 * MB);  // [1024][128]
    u16* Wh0T = (u16*)(ws + 36 * MB);  // [1024][1024]
    u16* Wx1T = (u16*)(ws + 38 * MB);
    u16* Wh1T = (u16*)(ws + 40 * MB);  // ..42 MB

    // phase 0 reads h0[-1] from h0b[1]; phase 1 reads h1[-1] from h1b[1]
    hipMemsetAsync(h0b[1], 0, 8 * MB, stream);
    hipMemsetAsync(h1b[1], 0, 8 * MB, stream);

    embed_pad<<<V_ * 128 / 256, 256, 0, stream>>>(emb, embP);
    transpose_pad<<<dim3(128 / 32, U_ / 32), 256, 0, stream>>>(Wx0, Wx0T, E_, U_, 128);
    transpose_pad<<<dim3(U_ / 32, U_ / 32), 256, 0, stream>>>(Wh0, Wh0T, U_, U_, U_);
    transpose_pad<<<dim3(U_ / 32, U_ / 32), 256, 0, stream>>>(Wx1, Wx1T, U_, U_, U_);
    transpose_pad<<<dim3(U_ / 32, U_ / 32), 256, 0, stream>>>(Wh1, Wh1T, U_, U_, U_);

    // phase p: layer0 writes h0[p] -> h0b[p&1], reads h0[p-1] -> h0b[(p&1)^1];
    //          layer1 writes h1[p-1] -> h1b[(p&1)^1], reads h1[p-2] -> h1b[p&1]
    // 256 linear blocks: layer = linear&1 (even=layer0) -> chunked-XCD n0 locality.
    for (int p = 0; p <= T_; ++p) {
        const int e = p & 1;
        rnn_phase<<<256, 512, 0, stream>>>(embP, inputs + p,
                                           Wx0T, Wh0T, b0, Wx1T, Wh1T, b1,
                                           h0b[e ^ 1], h0b[e], h1b[e], h1b[e ^ 1],
                                           (int)(p < T_), (int)(p >= 1));
    }
    // h1[79] written at phase 80 into h1b[(80&1)^1] = h1b[1]
    final_dense<<<B_ / 4, 256, 0, stream>>>(h1b[1], Wfc, bfc, (float*)d_out);
}

// Round 7
// 2954.121 us; speedup vs baseline: 1.1240x; 1.0858x over previous
//
#include <hip/hip_runtime.h>
#include <stdint.h>

#define B_ 4096
#define T_ 80
#define E_ 100
#define V_ 10000
#define U_ 1024

typedef unsigned short u16;
typedef __attribute__((ext_vector_type(8))) __bf16 bf16x8;
typedef __attribute__((ext_vector_type(4))) float f32x4;

__device__ __forceinline__ float bf2f(u16 u) {
    union { unsigned int i; float f; } v; v.i = ((unsigned int)u) << 16; return v.f;
}
__device__ __forceinline__ u16 f2bf(float f) {
    union { float f; unsigned int i; } v; v.f = f;
    unsigned int x = v.i;
    return (u16)((x + 0x7fffu + ((x >> 16) & 1u)) >> 16);
}

// async global->LDS, 16 B per lane; LDS dest = wave-uniform base + lane*16 (m104 semantics).
__device__ __forceinline__ void load16(const void* g, void* l) {
    __builtin_amdgcn_global_load_lds(
        (__attribute__((address_space(1))) void*)(uintptr_t)g,
        (__attribute__((address_space(3))) void*)(uint32_t)(uintptr_t)l,
        16, 0, 0);
}

// dst[n*Kp + k] = bf16( (k < K) ? src[k*N + n] : 0 )
__global__ void transpose_pad(const float* __restrict__ src, u16* __restrict__ dst,
                              int K, int N, int Kp)
{
    __shared__ u16 tile[32][33];
    const int k0 = blockIdx.x * 32;
    const int n0 = blockIdx.y * 32;
    const int tx = threadIdx.x & 31;
    const int ty = threadIdx.x >> 5;
#pragma unroll
    for (int i = 0; i < 4; i++) {
        int k = k0 + ty + i * 8;
        tile[ty + i * 8][tx] = (k < K) ? f2bf(src[(size_t)k * N + (n0 + tx)]) : (u16)0;
    }
    __syncthreads();
#pragma unroll
    for (int i = 0; i < 4; i++) {
        int n = n0 + ty + i * 8;
        dst[(size_t)n * Kp + (k0 + tx)] = tile[tx][ty + i * 8];
    }
}

__global__ void embed_pad(const float* __restrict__ emb, u16* __restrict__ dst)
{
    int id = blockIdx.x * 256 + threadIdx.x;
    int v = id >> 7, k = id & 127;
    dst[id] = (k < E_) ? f2bf(emb[v * E_ + k]) : (u16)0;
}

// Fused phase p (independent sub-steps):
//   layer0: h0[p]   = tanh(embP[idx_p] @ Wx0 + h0[p-1] @ Wh0 + b0)   (if do0)
//   layer1: h1[p-1] = tanh(h0[p-1] @ Wx1 + h1[p-2] @ Wh1 + b1)       (if do1)
// r16: XCD-local h-state partitioning on the r12-proven (2818 us) kernel. Evidence trail:
// r12 balance neutral, r13 n0-per-XCD -9%, r15 depth-2 counted-vmcnt prefetch NEUTRAL
// (per-dispatch 38.2 vs 37.8 us) -> not prefetch-depth/balance/B-locality/bank-bound.
// Standing theory: A-panels are h-state written by the PREVIOUS dispatch; under chunked
// dispatch (the model consistent with r12+r13), every XCD writes all m-rows (owns
// n-stripes) so p+1's A-reads are cross-XCD dirty-line fetches (~210 MB/dispatch through
// the coherence path) -> high latency, low throughput, insensitive to prefetch depth.
// Fix: chunk c = linear>>6 (64 consecutive blocks = one XCD) owns h-rows [512c, 512c+512)
// for BOTH write and read, both layers: layer = j&1 (keeps r12 balance), m0 = 512c +
// (s&3)*128, n0 = (s>>2)*128. h stays in the local L2 across phases (~2 MB unique/XCD,
// ~16x reuse); only read-only weights stream from L3; C-writes L2-local. If the chunked
// model is wrong this is another permutation ~ neutral (r12 precedent).
// Tile M=128 x N=128 (wave tile 64x64, 4x4 frags), BK=64, dbuf -> 64 KB LDS ->
// 2 blocks/CU, grid 512 = all-resident. XOR swizzle (r6-proven, 0 conflicts).
__global__ void __launch_bounds__(256, 2)
rnn_phase(const u16* __restrict__ embP, const int* __restrict__ idx,
          const u16* __restrict__ Wx0T, const u16* __restrict__ Wh0T, const float* __restrict__ b0,
          const u16* __restrict__ Wx1T, const u16* __restrict__ Wh1T, const float* __restrict__ b1,
          const u16* __restrict__ h0r, u16* __restrict__ h0w,
          const u16* __restrict__ h1r, u16* __restrict__ h1w,
          int do0, int do1)
{
    const int linear = blockIdx.x;        // 0..511
    const int xcd    = linear >> 6;       // chunk of 64 consecutive blocks -> one XCD
    const int j      = linear & 63;
    const int layer  = j & 1;             // interleaved -> balanced CU pairing
    if (layer ? !do1 : !do0) return;

    __shared__ u16 As[2][128 * 64];   // 2 x 16 KB
    __shared__ u16 Bs[2][128 * 64];   // 2 x 16 KB
    const int tid  = threadIdx.x;
    const int lane = tid & 63;
    const int wave = tid >> 6;
    const int wm = wave >> 1, wn = wave & 1;
    const int s  = j >> 1;                // 0..31
    const int m0 = xcd * 512 + (s & 3) * 128;   // XCD-local 512-row m range
    const int n0 = (s >> 2) * 128;              // all 8 n-stripes within the XCD

    const u16 *A1, *W1, *A2, *W2; const float* bias; u16* C; int K1; bool gather;
    if (layer == 0) { A1 = embP; W1 = Wx0T; K1 = 128;  gather = true;  A2 = h0r; W2 = Wh0T; bias = b0; C = h0w; }
    else            { A1 = h0r;  W1 = Wx1T; K1 = 1024; gather = false; A2 = h1r; W2 = Wh1T; bias = b1; C = h1w; }
    const int KB1 = K1 >> 6;            // 64-wide K blocks in the first segment
    const int TOT = KB1 + (U_ >> 6);    // + 16 for the hidden segment

    // staging: per wave, A rows [wave*32,+32) in 4 calls, B rows [wave*32,+32) in 4 calls.
    // lane -> row += (lane>>3), chunk lane&7, source col chunk = (lane&7) ^ (row&7).
    const int r8 = lane >> 3;           // 0..7
    const int c8 = lane & 7;            // chunk index 0..7

    int gv[4];
    if (gather) {
#pragma unroll
        for (int cc = 0; cc < 4; cc++)
            gv[cc] = idx[(size_t)(m0 + wave * 32 + cc * 8 + r8) * T_];
    }

    const f32x4 z = {0.f, 0.f, 0.f, 0.f};
    f32x4 acc[4][4];
#pragma unroll
    for (int i = 0; i < 4; i++)
#pragma unroll
        for (int j2 = 0; j2 < 4; j2++) acc[i][j2] = z;

    // loop-invariant fragment read offsets (u16 elems), inverse-swizzled
    const int l15 = lane & 15, q = lane >> 4, l7 = lane & 7;
    int offA[2][4], offB[2][4];
#pragma unroll
    for (int kk = 0; kk < 2; kk++) {
#pragma unroll
        for (int f = 0; f < 4; f++) {
            const int rA = wm * 64 + f * 16 + l15;
            const int rB = wn * 64 + f * 16 + l15;
            offA[kk][f] = rA * 64 + (((kk * 4 + q) ^ l7) * 8);
            offB[kk][f] = rB * 64 + (((kk * 4 + q) ^ l7) * 8);
        }
    }

    auto stage = [&](int u, int p) {
        u16* Ad = As[p] + wave * 2048;   // 32 rows x 64 elems
        u16* Bd = Bs[p] + wave * 2048;   // 32 rows x 64 elems
        if (u < KB1) {
            const int k0 = u * 64;
#pragma unroll
            for (int cc = 0; cc < 4; cc++) {
                const int row = wave * 32 + cc * 8 + r8;
                const int scw = (c8 ^ (row & 7)) * 8;
                const u16* ap = gather ? A1 + (size_t)gv[cc] * 128 + k0 + scw
                                       : A1 + (size_t)(m0 + row) * K1 + k0 + scw;
                load16(ap, Ad + cc * 512);
                load16(W1 + (size_t)(n0 + row) * K1 + k0 + scw, Bd + cc * 512);
            }
        } else {
            const int k0 = (u - KB1) * 64;
#pragma unroll
            for (int cc = 0; cc < 4; cc++) {
                const int row = wave * 32 + cc * 8 + r8;
                const int scw = (c8 ^ (row & 7)) * 8;
                load16(A2 + (size_t)(m0 + row) * U_ + k0 + scw, Ad + cc * 512);
                load16(W2 + (size_t)(n0 + row) * U_ + k0 + scw, Bd + cc * 512);
            }
        }
    };

    stage(0, 0);

#pragma unroll 1
    for (int u = 0; u < TOT; ++u) {
        const int p = u & 1;
        __syncthreads();                       // vmcnt(0) drain -> buf[p] ready
        if (u + 1 < TOT) stage(u + 1, p ^ 1);  // flight overlaps this iter's compute
#pragma unroll
        for (int kk = 0; kk < 2; kk++) {
            bf16x8 a[4], b[4];
#pragma unroll
            for (int f = 0; f < 4; f++) {
                a[f] = *reinterpret_cast<const bf16x8*>(As[p] + offA[kk][f]);
                b[f] = *reinterpret_cast<const bf16x8*>(Bs[p] + offB[kk][f]);
            }
#pragma unroll
            for (int i = 0; i < 4; i++)
#pragma unroll
                for (int j2 = 0; j2 < 4; j2++)
                    acc[i][j2] = __builtin_amdgcn_mfma_f32_16x16x32_bf16(a[i], b[j2], acc[i][j2], 0, 0, 0);
        }
    }

    // epilogue: bias + tanh, bf16 store (C/D map: col = lane&15, row = (lane>>4)*4 + reg)
#pragma unroll
    for (int j2 = 0; j2 < 4; j2++) {
        const int col = n0 + wn * 64 + j2 * 16 + l15;
        const float bv = bias[col];
#pragma unroll
        for (int i = 0; i < 4; i++) {
#pragma unroll
            for (int r = 0; r < 4; r++) {
                const int row = m0 + wm * 64 + i * 16 + (q << 2) + r;
                float x = acc[i][j2][r] + bv;
                x = fminf(15.f, fmaxf(-15.f, x));
                float e = __expf(2.f * x);
                C[(size_t)row * U_ + col] = f2bf((e - 1.f) / (e + 1.f));
            }
        }
    }
}

// out[b] = sigmoid( dot(h1[b,:], Wfc) + bfc ), one wave per row; f32 out
__global__ void final_dense(const u16* __restrict__ h1, const float* __restrict__ Wfc,
                            const float* __restrict__ bfc, float* __restrict__ out)
{
    const int lane = threadIdx.x & 63;
    const int wave = threadIdx.x >> 6;
    const int row = blockIdx.x * 4 + wave;
    const u16* hp = h1 + (size_t)row * U_ + lane * 16;
    const float* wp = Wfc + lane * 16;
    float s = 0.f;
#pragma unroll
    for (int i = 0; i < 16; i++) s += bf2f(hp[i]) * wp[i];
#pragma unroll
    for (int off = 32; off; off >>= 1) s += __shfl_down(s, off);
    if (lane == 0) {
        float x = s + bfc[0];
        out[row] = 1.f / (1.f + __expf(-x));
    }
}

extern "C" void kernel_launch(void* const* d_in, const int* in_sizes, int n_in,
                              void* d_out, int out_size, void* d_ws, size_t ws_size,
                              hipStream_t stream)
{
    const int*   inputs = (const int*)d_in[0];
    const float* emb    = (const float*)d_in[1];
    const float* Wx0    = (const float*)d_in[2];
    const float* Wh0    = (const float*)d_in[3];
    const float* b0     = (const float*)d_in[4];
    const float* Wx1    = (const float*)d_in[5];
    const float* Wh1    = (const float*)d_in[6];
    const float* b1     = (const float*)d_in[7];
    const float* Wfc    = (const float*)d_in[8];
    const float* bfc    = (const float*)d_in[9];

    char* ws = (char*)d_ws;
    const size_t MB = 1 << 20;
    u16* h0b[2] = { (u16*)(ws + 0 * MB), (u16*)(ws + 8 * MB) };   // 8 MB each
    u16* h1b[2] = { (u16*)(ws + 16 * MB), (u16*)(ws + 24 * MB) };
    u16* embP = (u16*)(ws + 32 * MB);  // 2.56 MB
    u16* Wx0T = (u16*)(ws + 35 * MB);  // [1024][128]
    u16* Wh0T = (u16*)(ws + 36 * MB);  // [1024][1024]
    u16* Wx1T = (u16*)(ws + 38 * MB);
    u16* Wh1T = (u16*)(ws + 40 * MB);  // ..42 MB

    // phase 0 reads h0[-1] from h0b[1]; phase 1 reads h1[-1] from h1b[1]
    hipMemsetAsync(h0b[1], 0, 8 * MB, stream);
    hipMemsetAsync(h1b[1], 0, 8 * MB, stream);

    embed_pad<<<V_ * 128 / 256, 256, 0, stream>>>(emb, embP);
    transpose_pad<<<dim3(128 / 32, U_ / 32), 256, 0, stream>>>(Wx0, Wx0T, E_, U_, 128);
    transpose_pad<<<dim3(U_ / 32, U_ / 32), 256, 0, stream>>>(Wh0, Wh0T, U_, U_, U_);
    transpose_pad<<<dim3(U_ / 32, U_ / 32), 256, 0, stream>>>(Wx1, Wx1T, U_, U_, U_);
    transpose_pad<<<dim3(U_ / 32, U_ / 32), 256, 0, stream>>>(Wh1, Wh1T, U_, U_, U_);

    // phase p: layer0 writes h0[p] -> h0b[p&1], reads h0[p-1] -> h0b[(p&1)^1];
    //          layer1 writes h1[p-1] -> h1b[(p&1)^1], reads h1[p-2] -> h1b[p&1]
    // 512 linear blocks; chunk of 64 -> one XCD owns a 512-row m range (both layers).
    for (int p = 0; p <= T_; ++p) {
        const int e = p & 1;
        rnn_phase<<<512, 256, 0, stream>>>(embP, inputs + p,
                                           Wx0T, Wh0T, b0, Wx1T, Wh1T, b1,
                                           h0b[e ^ 1], h0b[e], h1b[e], h1b[e ^ 1],
                                           (int)(p < T_), (int)(p >= 1));
    }
    // h1[79] written at phase 80 into h1b[(80&1)^1] = h1b[1]
    final_dense<<<B_ / 4, 256, 0, stream>>>(h1b[1], Wfc, bfc, (float*)d_out);
}